// Round 13
// baseline (197.429 us; speedup 1.0000x reference)
//
#include <hip/hip_runtime.h>
#include <cstdint>

// MHA forward, B=2 S=2048 D=1024 H=16 hd=64, fp32 I/O, bf16 MFMA internal.
// cast_all -> fused QKV GEMM (128x128, BK=32, dbuf global_load_lds,
// LDS-bounced epilogue; V segment stored TRANSPOSED directly) -> causal
// flash attn (r8 structure + setprio: 256 thr = 4 waves x 32 q-rows,
// reg-staged dbuf K/V LDS stride-72, one barrier/iter, swapped QK^T
// [mfma(K,Q)] -> P as 8 ds_write_b64 read back as PV A-frags, exp2 softmax,
// l via ones-MFMA, in-reg normalize, coalesced bf16 out)
// -> O-proj GEMM (128x64, BK=64: two 32-k subtiles per buffer -> HALF the
// barrier/vmcnt drains, 16 MFMA/wave per interval; 48KB LDS, 2 blocks/CU).

typedef __bf16 bf16x8 __attribute__((ext_vector_type(8)));
typedef float f32x4 __attribute__((ext_vector_type(4)));

__device__ inline f32x4 mfma16(bf16x8 a, bf16x8 b, f32x4 c) {
    return __builtin_amdgcn_mfma_f32_16x16x32_bf16(a, b, c, 0, 0, 0);
}

__device__ inline uint16_t f2bf(float f) {
    uint32_t u = __builtin_bit_cast(uint32_t, f);
    u += 0x7FFFu + ((u >> 16) & 1u);   // RNE
    return (uint16_t)(u >> 16);
}

__device__ inline void gload_lds16(const uint16_t* g, uint16_t* l) {
    __builtin_amdgcn_global_load_lds(
        (const __attribute__((address_space(1))) uint32_t*)g,
        (__attribute__((address_space(3))) uint32_t*)l, 16, 0, 0);
}

// ---------------- fused cast: x (1M float4) + Wq/Wk/Wv/Wo (256K float4 each) ----------------
__global__ __launch_bounds__(256) void cast_all(const float* __restrict__ x,
                                                const float* __restrict__ wq,
                                                const float* __restrict__ wk,
                                                const float* __restrict__ wv,
                                                const float* __restrict__ wo,
                                                uint16_t* __restrict__ xbf,
                                                uint16_t* __restrict__ wbf) {
    int i = blockIdx.x * 256 + threadIdx.x;
    float4 v;
    uint64_t* dp;
    if (i < (1 << 20)) {
        v = ((const float4*)x)[i];
        dp = (uint64_t*)xbf + i;
    } else {
        int j = i - (1 << 20);
        const float* ws[4] = {wq, wk, wv, wo};
        v = ((const float4*)ws[j >> 18])[j & 0x3FFFF];
        dp = (uint64_t*)wbf + j;
    }
    uint64_t p = (uint64_t)f2bf(v.x) | ((uint64_t)f2bf(v.y) << 16) |
                 ((uint64_t)f2bf(v.z) << 32) | ((uint64_t)f2bf(v.w) << 48);
    *dp = p;
}

// ---------------- 128xBN BT-GEMM, double-buffered prefetch-after-barrier ----------------
// BN=128 (QKV): BK=32. bf16 out via LDS-bounce, EP stride 128. Q/K: coalesced
//   256B row stores. V (seg==2): stored TRANSPOSED into Vt.
// BN=64 (O-proj): BK=64 (KST=2 subtiles per buffer, each subtile uses the
//   proven BK=32 layout) -> 16 iters, half the barrier drains. fp32 direct
//   stores. 48KB LDS, 512-block grid = 2 blocks/CU.
template<int OUTF32, int BN>
__global__ __launch_bounds__(256) void gemm128(const uint16_t* __restrict__ A,
                                               const uint16_t* __restrict__ W,
                                               const float* __restrict__ b0,
                                               const float* __restrict__ b1,
                                               const float* __restrict__ b2,
                                               void* __restrict__ o0,
                                               void* __restrict__ o1,
                                               void* __restrict__ o2,
                                               int K, float s0, float s1, float s2) {
    constexpr int NT = BN / 32;             // acc cols per wave
    constexpr int KST = (BN == 64) ? 2 : 1; // 32-k subtiles per iter
    __shared__ __align__(16) uint16_t SH[2 * (128 + BN) * 32 * KST];
    const int tid = threadIdx.x;
    const int lane = tid & 63, w = tid >> 6;
    const int l16 = lane & 15, quad = lane >> 4;
    const int wm = w & 1, wn = w >> 1;
    const int m0 = blockIdx.x * 128, n0 = blockIdx.y * BN;

    f32x4 acc[4][NT] = {};

    const int ci0 = w * 128 + lane;
    const uint16_t* ga0 = A + (size_t)(m0 + (ci0 >> 2)) * K + (ci0 & 3) * 8;
    const int ci1 = ci0 + 64;
    const uint16_t* ga1 = A + (size_t)(m0 + (ci1 >> 2)) * K + (ci1 & 3) * 8;
    const uint16_t* gb0 = W + (size_t)(n0 + (ci0 >> 2)) * K + (ci0 & 3) * 8;  // BN=128
    const uint16_t* gb1 = W + (size_t)(n0 + (ci1 >> 2)) * K + (ci1 & 3) * 8;  // BN=128
    const uint16_t* gbS = W + (size_t)(n0 + (tid >> 2)) * K + (tid & 3) * 8;  // BN=64

    uint16_t* A0 = SH;
    uint16_t* B0 = SH + 128 * 32 * KST;
    uint16_t* A1 = SH + (128 + BN) * 32 * KST;
    uint16_t* B1 = A1 + 128 * 32 * KST;

    // stage tile i (KST subtiles) into (Ad,Bd)
    auto stage = [&](int i, uint16_t* Ad, uint16_t* Bd) {
#pragma unroll
        for (int kk = 0; kk < KST; ++kk) {
            const int k1 = i * 32 * KST + kk * 32;
            gload_lds16(ga0 + k1, Ad + kk * 128 * 32 + (w * 2 + 0) * 512);
            gload_lds16(ga1 + k1, Ad + kk * 128 * 32 + (w * 2 + 1) * 512);
            if constexpr (BN == 128) {
                gload_lds16(gb0 + k1, Bd + (w * 2 + 0) * 512);
                gload_lds16(gb1 + k1, Bd + (w * 2 + 1) * 512);
            } else {
                gload_lds16(gbS + k1, Bd + kk * 64 * 32 + w * 512);
            }
        }
    };

    // prologue: tile 0 -> buf 0
    stage(0, A0, B0);

    const int niter = K / (32 * KST);
    for (int i = 0; i < niter; ++i) {
        __syncthreads();
        if (i + 1 < niter)
            stage(i + 1, (i & 1) ? A0 : A1, (i & 1) ? B0 : B1);
        const uint16_t* Ab = (i & 1) ? A1 : A0;
        const uint16_t* Bb = (i & 1) ? B1 : B0;
#pragma unroll
        for (int kk = 0; kk < KST; ++kk) {
            bf16x8 af[4], bw[NT];
#pragma unroll
            for (int t = 0; t < 4; ++t)
                af[t] = *(const bf16x8*)(Ab + kk * 128 * 32 +
                                         (wm * 64 + t * 16 + l16) * 32 + quad * 8);
#pragma unroll
            for (int t = 0; t < NT; ++t)
                bw[t] = *(const bf16x8*)(Bb + kk * BN * 32 +
                                         (wn * (BN / 2) + t * 16 + l16) * 32 + quad * 8);
#pragma unroll
            for (int mt = 0; mt < 4; ++mt)
#pragma unroll
                for (int nt = 0; nt < NT; ++nt)
                    acc[mt][nt] = mfma16(af[mt], bw[nt], acc[mt][nt]);
        }
    }

    // block lies in a single 1024-col segment (BN divides 1024)
    const int seg = n0 >> 10, lc0 = n0 & 1023;
    const float* bp = (seg == 0) ? b0 : (seg == 1 ? b1 : b2);
    const float scale = (seg == 0) ? s0 : (seg == 1 ? s1 : s2);
    void* op = (seg == 0) ? o0 : (seg == 1 ? o1 : o2);

    if constexpr (OUTF32) {
        // fp32 direct stores: 16 lanes x 4B = 64B contiguous per quad-row
#pragma unroll
        for (int nt = 0; nt < NT; ++nt) {
            int lcol = lc0 + wn * (BN / 2) + nt * 16 + l16;
            float bc = bp[lcol];
#pragma unroll
            for (int mt = 0; mt < 4; ++mt)
#pragma unroll
                for (int r = 0; r < 4; ++r) {
                    int row = m0 + wm * 64 + mt * 16 + quad * 4 + r;
                    ((float*)op)[(size_t)row * 1024 + lcol] = (acc[mt][nt][r] + bc) * scale;
                }
        }
    } else {
        // bf16: bounce through LDS (staging bufs dead), stride 128 (16B-aligned)
        __syncthreads();
        uint16_t* EP = SH;                     // [128][128] bf16 = 32KB
#pragma unroll
        for (int nt = 0; nt < NT; ++nt) {
            float bc = bp[lc0 + wn * (BN / 2) + nt * 16 + l16];
#pragma unroll
            for (int mt = 0; mt < 4; ++mt)
#pragma unroll
                for (int r = 0; r < 4; ++r)
                    EP[(wm * 64 + mt * 16 + quad * 4 + r) * 128 +
                       wn * (BN / 2) + nt * 16 + l16] =
                        f2bf((acc[mt][nt][r] + bc) * scale);
        }
        __syncthreads();
        if (seg == 2) {
            // V segment: store transposed into Vt (op) = [(b*16+h)*64+d][s].
            const int bb = m0 >> 11, s0v = m0 & 2047;
            const int h0 = (n0 - 2048) >> 6;
            uint16_t* vtb = (uint16_t*)op + ((size_t)(bb * 16 + h0) * 64) * 2048 + s0v;
#pragma unroll
            for (int it = 0; it < 8; ++it) {
                int id = it * 256 + tid;
                int c = id & 127, sg = id >> 7;   // lanes vary c -> 2-way banks (free)
                uint32_t wpk[4];
#pragma unroll
                for (int jj = 0; jj < 4; ++jj) {
                    uint32_t lo = EP[(sg * 8 + 2 * jj) * 128 + c];
                    uint32_t hi = EP[(sg * 8 + 2 * jj + 1) * 128 + c];
                    wpk[jj] = lo | (hi << 16);
                }
                uint4 o; o.x = wpk[0]; o.y = wpk[1]; o.z = wpk[2]; o.w = wpk[3];
                *(uint4*)(vtb + (size_t)c * 2048 + sg * 8) = o;
            }
        } else {
            // Q/K segments: coalesced 256B row stores
#pragma unroll
            for (int p = 0; p < 8; ++p) {
                int row = p * 16 + (tid >> 4);
                int c8 = (tid & 15) * 8;
                uint4 v = *(const uint4*)(EP + row * 128 + c8);
                *(uint4*)((uint16_t*)op + (size_t)(m0 + row) * 1024 + lc0 + c8) = v;
            }
        }
    }
}

// ---------------- causal flash attention: 256 thr, 4 waves x 32 q-rows ----------------
// r8 structure + T5 setprio (r12-verified). BQ=128, BK=64, full K-range per
// block (2*qb+2 iters, max 32). Complementary qb pairing. K/V double-buffered
// in LDS (stride 72), reg-prefetched staging, one barrier per iter.
// SWAPPED QK^T: sc = mfma(K, Q) -> lane holds P^T fragment: q-row = l16,
// k-col = t*16 + quad*4 + r; 4 r-values LDS-contiguous -> one ds_write_b64
// per (mt,t) = 8 writes/iter; written layout IS the PV A-frag layout.
__global__ __launch_bounds__(256) void attn_kernel(const uint16_t* __restrict__ Q,
                                                   const uint16_t* __restrict__ K,
                                                   const uint16_t* __restrict__ Vt,
                                                   uint16_t* __restrict__ att) {
    const int S = 2048, D = 1024;
    constexpr int LD = 72;                      // 144B rows = 9*16B aligned
    __shared__ __align__(16) uint16_t Klds[2][64 * LD];
    __shared__ __align__(16) uint16_t Vlds[2][64 * LD];
    __shared__ __align__(16) uint16_t Plds[4 * 32 * LD];

    const int bh = blockIdx.y;
    // complementary pairing across the two dispatch halves
    const int qb = (bh & 16) ? (int)blockIdx.x : 15 - (int)blockIdx.x;
    const int niter = 2 * qb + 2, kb_diag = 2 * qb;

    const int b = bh >> 4, h = bh & 15;
    const int tid = threadIdx.x, lane = tid & 63, w = tid >> 6;
    const int l16 = lane & 15, quad = lane >> 4;
    const int q0 = qb * 128;
    const size_t baseQK = (size_t)b * S * D + h * 64;
    uint16_t* Pw = Plds + w * (32 * LD);

    bf16x8 aq[2][2];
#pragma unroll
    for (int mt = 0; mt < 2; ++mt)
#pragma unroll
        for (int c = 0; c < 2; ++c)
            aq[mt][c] = *(const bf16x8*)(Q + baseQK +
                (size_t)(q0 + w * 32 + mt * 16 + l16) * D + c * 32 + quad * 8);

    bf16x8 ones;
#pragma unroll
    for (int j = 0; j < 8; ++j) ones[j] = (__bf16)1.0f;

    f32x4 accO[2][4] = {};
    f32x4 accL[2] = {};

    const int srow = tid >> 2, scq = tid & 3;   // staging: 64 rows x 4 col-groups of 16
    const uint16_t* Kg = K + baseQK + (size_t)srow * D + scq * 16;
    const uint16_t* Vg = Vt + ((size_t)bh * 64 + srow) * S + scq * 16;
    const int soff = srow * LD + scq * 16;

    // prologue: tile 0 regs -> LDS buf0; prefetch tile 1 into regs; one barrier
    uint4 kA, kB, vA, vB;
    kA = *(const uint4*)Kg; kB = *(const uint4*)(Kg + 8);
    vA = *(const uint4*)Vg; vB = *(const uint4*)(Vg + 8);
    *(uint4*)(Klds[0] + soff)     = kA;
    *(uint4*)(Klds[0] + soff + 8) = kB;
    *(uint4*)(Vlds[0] + soff)     = vA;
    *(uint4*)(Vlds[0] + soff + 8) = vB;
    {
        const uint16_t* kg = Kg + (size_t)64 * D;   // niter >= 2 always
        const uint16_t* vg = Vg + 64;
        kA = *(const uint4*)kg; kB = *(const uint4*)(kg + 8);
        vA = *(const uint4*)vg; vB = *(const uint4*)(vg + 8);
    }
    __syncthreads();

    for (int kb = 0; kb < niter; ++kb) {
        const uint16_t* Kb = Klds[kb & 1];
        const uint16_t* Vb = Vlds[kb & 1];

        // stage tile kb+1 into the other buffer (WAR safe across the barrier)
        if (kb + 1 < niter) {
            uint16_t* Kd = (uint16_t*)Klds[(kb + 1) & 1];
            uint16_t* Vd = (uint16_t*)Vlds[(kb + 1) & 1];
            *(uint4*)(Kd + soff)     = kA;
            *(uint4*)(Kd + soff + 8) = kB;
            *(uint4*)(Vd + soff)     = vA;
            *(uint4*)(Vd + soff + 8) = vB;
            if (kb + 2 < niter) {
                const uint16_t* kg = Kg + (size_t)((kb + 2) * 64) * D;
                const uint16_t* vg = Vg + (kb + 2) * 64;
                kA = *(const uint4*)kg; kB = *(const uint4*)(kg + 8);
                vA = *(const uint4*)vg; vB = *(const uint4*)(vg + 8);
            }
        }

        // ---- SWAPPED QK^T: sc[mt][t] = K_t * Q_mt -> D[kcol][qrow] ----
        f32x4 sc[2][4];
        __builtin_amdgcn_s_setprio(1);
#pragma unroll
        for (int t = 0; t < 4; ++t) {
            bf16x8 bk0 = *(const bf16x8*)(Kb + (t * 16 + l16) * LD + quad * 8);
            bf16x8 bk1 = *(const bf16x8*)(Kb + (t * 16 + l16) * LD + 32 + quad * 8);
            f32x4 z0 = {}; f32x4 z1 = {};
            sc[0][t] = mfma16(bk1, aq[0][1], mfma16(bk0, aq[0][0], z0));
            sc[1][t] = mfma16(bk1, aq[1][1], mfma16(bk0, aq[1][0], z1));
        }
        __builtin_amdgcn_s_setprio(0);

        // ---- V frags early ----
        bf16x8 bv0[4], bv1[4];
#pragma unroll
        for (int nt = 0; nt < 4; ++nt) {
            bv0[nt] = *(const bf16x8*)(Vb + (nt * 16 + l16) * LD + quad * 8);
            bv1[nt] = *(const bf16x8*)(Vb + (nt * 16 + l16) * LD + 32 + quad * 8);
        }

        // ---- p = 2^s (truncate to bf16), pack 4 r-values -> one b64 store ----
        // Pw[qrow][k] with qrow = mt*16+l16, k = t*16+quad*4+r  (A-frag layout)
        if (kb < kb_diag) {
#pragma unroll
            for (int mt = 0; mt < 2; ++mt) {
                uint16_t* prow = Pw + (mt * 16 + l16) * LD + quad * 4;
#pragma unroll
                for (int t = 0; t < 4; ++t) {
                    uint64_t pk = 0;
#pragma unroll
                    for (int r = 0; r < 4; ++r) {
                        float p = __builtin_amdgcn_exp2f(sc[mt][t][r]);
                        pk |= (uint64_t)(uint16_t)(__builtin_bit_cast(uint32_t, p) >> 16)
                              << (16 * r);
                    }
                    *(uint64_t*)(prow + t * 16) = pk;
                }
            }
        } else {
#pragma unroll
            for (int mt = 0; mt < 2; ++mt) {
                const int qrow = q0 + w * 32 + mt * 16 + l16;
                uint16_t* prow = Pw + (mt * 16 + l16) * LD + quad * 4;
#pragma unroll
                for (int t = 0; t < 4; ++t) {
                    const int kc0 = kb * 64 + t * 16 + quad * 4;
                    uint64_t pk = 0;
#pragma unroll
                    for (int r = 0; r < 4; ++r) {
                        float s = sc[mt][t][r];
                        if (kc0 + r > qrow) s = -1e30f;
                        float p = __builtin_amdgcn_exp2f(s);
                        pk |= (uint64_t)(uint16_t)(__builtin_bit_cast(uint32_t, p) >> 16)
                              << (16 * r);
                    }
                    *(uint64_t*)(prow + t * 16) = pk;
                }
            }
        }

        __asm__ volatile("s_waitcnt lgkmcnt(0)" ::: "memory");

        bf16x8 ap0[2], ap1[2];
#pragma unroll
        for (int mt = 0; mt < 2; ++mt) {
            ap0[mt] = *(const bf16x8*)(Pw + (mt * 16 + l16) * LD + quad * 8);
            ap1[mt] = *(const bf16x8*)(Pw + (mt * 16 + l16) * LD + 32 + quad * 8);
        }
        __builtin_amdgcn_s_setprio(1);
#pragma unroll
        for (int nt = 0; nt < 4; ++nt) {
            accO[0][nt] = mfma16(ap1[0], bv1[nt], mfma16(ap0[0], bv0[nt], accO[0][nt]));
            accO[1][nt] = mfma16(ap1[1], bv1[nt], mfma16(ap0[1], bv0[nt], accO[1][nt]));
        }
        // l row-sums of the exact stored bf16 P (all 16 output cols equal)
        accL[0] = mfma16(ap1[0], ones, mfma16(ap0[0], ones, accL[0]));
        accL[1] = mfma16(ap1[1], ones, mfma16(ap0[1], ones, accL[1]));
        __builtin_amdgcn_s_setprio(0);

        if (kb + 1 < niter) __syncthreads();   // publishes buf (kb+1)&1
    }

    // ---- normalize into per-wave Pw (32x64 bf16), coalesced stores ----
    __asm__ volatile("s_waitcnt lgkmcnt(0)" ::: "memory");  // ap frag reads done
#pragma unroll
    for (int mt = 0; mt < 2; ++mt)
#pragma unroll
        for (int r = 0; r < 4; ++r) {
            float inv = __builtin_amdgcn_rcpf(accL[mt][r]);
            const int rl = mt * 16 + quad * 4 + r;
#pragma unroll
            for (int nt = 0; nt < 4; ++nt)
                Pw[rl * LD + nt * 16 + l16] = f2bf(accO[mt][nt][r] * inv);
        }
    __asm__ volatile("s_waitcnt lgkmcnt(0)" ::: "memory");
#pragma unroll
    for (int p = 0; p < 4; ++p) {
        int row = p * 8 + (lane >> 3);          // 0..31 within wave's q-rows
        int c8 = (lane & 7) * 8;                // 0..56 within head dims (16B steps)
        uint4 v = *(const uint4*)(Pw + row * LD + c8);
        *(uint4*)(att + (size_t)(b * S + q0 + w * 32 + row) * 1024 + h * 64 + c8) = v;
    }
}

extern "C" void kernel_launch(void* const* d_in, const int* in_sizes, int n_in,
                              void* d_out, int out_size, void* d_ws, size_t ws_size,
                              hipStream_t stream) {
    const float* x  = (const float*)d_in[0];
    // d_in[1] = mask: known causal, unused
    const float* Wq = (const float*)d_in[2];
    const float* bq = (const float*)d_in[3];
    const float* Wk = (const float*)d_in[4];
    const float* bk = (const float*)d_in[5];
    const float* Wv = (const float*)d_in[6];
    const float* bv = (const float*)d_in[7];
    const float* Wo = (const float*)d_in[8];
    const float* bo = (const float*)d_in[9];
    float* out = (float*)d_out;

    const int B = 2, S = 2048, D = 1024, H = 16;
    const int M = B * S;  // 4096

    uint8_t* w = (uint8_t*)d_ws;
    uint16_t* xbf  = (uint16_t*)(w);                       // 8 MB (aliased by att)
    uint16_t* wqbf = (uint16_t*)(w + (size_t)( 8 << 20));  // wq/wk/wv/wo contiguous
    uint16_t* qbf  = (uint16_t*)(w + (size_t)(16 << 20));
    uint16_t* kbf  = (uint16_t*)(w + (size_t)(24 << 20));
    uint16_t* vtbf = (uint16_t*)(w + (size_t)(40 << 20));  // V written transposed by QKV GEMM
    uint16_t* wobf = wqbf + (size_t)3 * D * D;
    uint16_t* attbf = xbf;                                 // x dead after QKV GEMM

    // fused cast: x (1<<20 float4) + 4 weights (4 * 1<<18 float4) = 1<<21 quads
    cast_all<<<dim3((1 << 21) / 256), dim3(256), 0, stream>>>(
        x, Wq, Wk, Wv, Wo, xbf, wqbf);

    // fused QKV: A[4096,1024] x W[3072,1024]^T ; Q scaled by 0.125*log2(e);
    // V segment written transposed into vtbf (o2)
    gemm128<0, 128><<<dim3(M / 128, 3072 / 128), dim3(256), 0, stream>>>(
        xbf, wqbf, bq, bk, bv, qbf, kbf, vtbf, D, 0.125f * 1.44269504f, 1.0f, 1.0f);

    // causal attention: 16 q-blocks x 32 (b,h), 256 threads, complementary pairing
    attn_kernel<<<dim3(16, B * H), dim3(256), 0, stream>>>(qbf, kbf, vtbf, attbf);

    // O-proj: 128x64 tiles, BK=64 -> 512 blocks = 2 blocks/CU, 16 iters
    gemm128<1, 64><<<dim3(M / 128, 1024 / 64), dim3(256), 0, stream>>>(
        attbf, wobf, bo, bo, bo, out, out, out, D, 1.0f, 1.0f, 1.0f);
}

// Round 14
// 192.340 us; speedup vs baseline: 1.0265x; 1.0265x over previous
//
#include <hip/hip_runtime.h>
#include <cstdint>

// MHA forward, B=2 S=2048 D=1024 H=16 hd=64, fp32 I/O, bf16 MFMA internal.
// cast_all -> fused QKV GEMM (128x128, BK=32, dbuf global_load_lds,
// LDS-bounced epilogue; V segment stored TRANSPOSED directly) -> causal
// flash attn (r12-verified structure: 256 thr = 4 waves x 32 q-rows,
// reg-staged dbuf K/V LDS stride-72, one barrier/iter, swapped QK^T
// [mfma(K,Q)] -> P as 8 ds_write_b64 read back as PV A-frags, exp2 softmax,
// l via ones-MFMA, setprio around MFMA clusters, CAUSAL WAVE EARLY-EXIT
// [waves 0,1 skip the fully-masked final K-tile], in-reg normalize,
// coalesced bf16 out) -> O-proj GEMM (128x64, BK=32, 512 blocks = 2/CU).

typedef __bf16 bf16x8 __attribute__((ext_vector_type(8)));
typedef float f32x4 __attribute__((ext_vector_type(4)));

__device__ inline f32x4 mfma16(bf16x8 a, bf16x8 b, f32x4 c) {
    return __builtin_amdgcn_mfma_f32_16x16x32_bf16(a, b, c, 0, 0, 0);
}

__device__ inline uint16_t f2bf(float f) {
    uint32_t u = __builtin_bit_cast(uint32_t, f);
    u += 0x7FFFu + ((u >> 16) & 1u);   // RNE
    return (uint16_t)(u >> 16);
}

__device__ inline void gload_lds16(const uint16_t* g, uint16_t* l) {
    __builtin_amdgcn_global_load_lds(
        (const __attribute__((address_space(1))) uint32_t*)g,
        (__attribute__((address_space(3))) uint32_t*)l, 16, 0, 0);
}

// ---------------- fused cast: x (1M float4) + Wq/Wk/Wv/Wo (256K float4 each) ----------------
__global__ __launch_bounds__(256) void cast_all(const float* __restrict__ x,
                                                const float* __restrict__ wq,
                                                const float* __restrict__ wk,
                                                const float* __restrict__ wv,
                                                const float* __restrict__ wo,
                                                uint16_t* __restrict__ xbf,
                                                uint16_t* __restrict__ wbf) {
    int i = blockIdx.x * 256 + threadIdx.x;
    float4 v;
    uint64_t* dp;
    if (i < (1 << 20)) {
        v = ((const float4*)x)[i];
        dp = (uint64_t*)xbf + i;
    } else {
        int j = i - (1 << 20);
        const float* ws[4] = {wq, wk, wv, wo};
        v = ((const float4*)ws[j >> 18])[j & 0x3FFFF];
        dp = (uint64_t*)wbf + j;
    }
    uint64_t p = (uint64_t)f2bf(v.x) | ((uint64_t)f2bf(v.y) << 16) |
                 ((uint64_t)f2bf(v.z) << 32) | ((uint64_t)f2bf(v.w) << 48);
    *dp = p;
}

// ---------------- 128xBN BT-GEMM, double-buffered prefetch-after-barrier ----------------
// BN=128 (QKV): bf16 out via LDS-bounce, EP stride 128. Q/K: coalesced 256B
//   row stores. V (seg==2): stored TRANSPOSED into Vt = [(b*16+h)*64+d][s].
// BN=64 (O-proj): fp32 direct stores, 24KB LDS, 512-block grid = 2/CU.
template<int OUTF32, int BN>
__global__ __launch_bounds__(256) void gemm128(const uint16_t* __restrict__ A,
                                               const uint16_t* __restrict__ W,
                                               const float* __restrict__ b0,
                                               const float* __restrict__ b1,
                                               const float* __restrict__ b2,
                                               void* __restrict__ o0,
                                               void* __restrict__ o1,
                                               void* __restrict__ o2,
                                               int K, float s0, float s1, float s2) {
    constexpr int NT = BN / 32;             // acc cols per wave
    __shared__ __align__(16) uint16_t SH[2 * (128 + BN) * 32];   // >= 128*128 when BN=128
    const int tid = threadIdx.x;
    const int lane = tid & 63, w = tid >> 6;
    const int l16 = lane & 15, quad = lane >> 4;
    const int wm = w & 1, wn = w >> 1;
    const int m0 = blockIdx.x * 128, n0 = blockIdx.y * BN;

    f32x4 acc[4][NT] = {};

    const int ci0 = w * 128 + lane;
    const uint16_t* ga0 = A + (size_t)(m0 + (ci0 >> 2)) * K + (ci0 & 3) * 8;
    const int ci1 = ci0 + 64;
    const uint16_t* ga1 = A + (size_t)(m0 + (ci1 >> 2)) * K + (ci1 & 3) * 8;
    const uint16_t* gb0 = W + (size_t)(n0 + (ci0 >> 2)) * K + (ci0 & 3) * 8;  // BN=128
    const uint16_t* gb1 = W + (size_t)(n0 + (ci1 >> 2)) * K + (ci1 & 3) * 8;  // BN=128
    const uint16_t* gbS = W + (size_t)(n0 + (tid >> 2)) * K + (tid & 3) * 8;  // BN=64

    uint16_t* A0 = SH;
    uint16_t* B0 = SH + 128 * 32;
    uint16_t* A1 = SH + (128 + BN) * 32;
    uint16_t* B1 = A1 + 128 * 32;

    // prologue: tile 0 -> buf 0
    gload_lds16(ga0, A0 + (w * 2 + 0) * 512);
    gload_lds16(ga1, A0 + (w * 2 + 1) * 512);
    if constexpr (BN == 128) {
        gload_lds16(gb0, B0 + (w * 2 + 0) * 512);
        gload_lds16(gb1, B0 + (w * 2 + 1) * 512);
    } else {
        gload_lds16(gbS, B0 + w * 512);
    }

    const int niter = K >> 5;
    for (int i = 0; i < niter; ++i) {
        __syncthreads();
        if (i + 1 < niter) {
            const int k1 = (i + 1) << 5;
            uint16_t* Ad = (i & 1) ? A0 : A1;
            uint16_t* Bd = (i & 1) ? B0 : B1;
            gload_lds16(ga0 + k1, Ad + (w * 2 + 0) * 512);
            gload_lds16(ga1 + k1, Ad + (w * 2 + 1) * 512);
            if constexpr (BN == 128) {
                gload_lds16(gb0 + k1, Bd + (w * 2 + 0) * 512);
                gload_lds16(gb1 + k1, Bd + (w * 2 + 1) * 512);
            } else {
                gload_lds16(gbS + k1, Bd + w * 512);
            }
        }
        const uint16_t* Ab = (i & 1) ? A1 : A0;
        const uint16_t* Bb = (i & 1) ? B1 : B0;
        bf16x8 af[4], bw[NT];
#pragma unroll
        for (int t = 0; t < 4; ++t)
            af[t] = *(const bf16x8*)(Ab + (wm * 64 + t * 16 + l16) * 32 + quad * 8);
#pragma unroll
        for (int t = 0; t < NT; ++t)
            bw[t] = *(const bf16x8*)(Bb + (wn * (BN / 2) + t * 16 + l16) * 32 + quad * 8);
#pragma unroll
        for (int mt = 0; mt < 4; ++mt)
#pragma unroll
            for (int nt = 0; nt < NT; ++nt)
                acc[mt][nt] = mfma16(af[mt], bw[nt], acc[mt][nt]);
    }

    // block lies in a single 1024-col segment (BN divides 1024)
    const int seg = n0 >> 10, lc0 = n0 & 1023;
    const float* bp = (seg == 0) ? b0 : (seg == 1 ? b1 : b2);
    const float scale = (seg == 0) ? s0 : (seg == 1 ? s1 : s2);
    void* op = (seg == 0) ? o0 : (seg == 1 ? o1 : o2);

    if constexpr (OUTF32) {
        // fp32 direct stores: 16 lanes x 4B = 64B contiguous per quad-row
#pragma unroll
        for (int nt = 0; nt < NT; ++nt) {
            int lcol = lc0 + wn * (BN / 2) + nt * 16 + l16;
            float bc = bp[lcol];
#pragma unroll
            for (int mt = 0; mt < 4; ++mt)
#pragma unroll
                for (int r = 0; r < 4; ++r) {
                    int row = m0 + wm * 64 + mt * 16 + quad * 4 + r;
                    ((float*)op)[(size_t)row * 1024 + lcol] = (acc[mt][nt][r] + bc) * scale;
                }
        }
    } else {
        // bf16: bounce through LDS (staging bufs dead), stride 128 (16B-aligned)
        __syncthreads();
        uint16_t* EP = SH;                     // [128][128] bf16 = 32KB
#pragma unroll
        for (int nt = 0; nt < NT; ++nt) {
            float bc = bp[lc0 + wn * (BN / 2) + nt * 16 + l16];
#pragma unroll
            for (int mt = 0; mt < 4; ++mt)
#pragma unroll
                for (int r = 0; r < 4; ++r)
                    EP[(wm * 64 + mt * 16 + quad * 4 + r) * 128 +
                       wn * (BN / 2) + nt * 16 + l16] =
                        f2bf((acc[mt][nt][r] + bc) * scale);
        }
        __syncthreads();
        if (seg == 2) {
            // V segment: store transposed into Vt (op) = [(b*16+h)*64+d][s].
            const int bb = m0 >> 11, s0v = m0 & 2047;
            const int h0 = (n0 - 2048) >> 6;
            uint16_t* vtb = (uint16_t*)op + ((size_t)(bb * 16 + h0) * 64) * 2048 + s0v;
#pragma unroll
            for (int it = 0; it < 8; ++it) {
                int id = it * 256 + tid;
                int c = id & 127, sg = id >> 7;   // lanes vary c -> 2-way banks (free)
                uint32_t wpk[4];
#pragma unroll
                for (int jj = 0; jj < 4; ++jj) {
                    uint32_t lo = EP[(sg * 8 + 2 * jj) * 128 + c];
                    uint32_t hi = EP[(sg * 8 + 2 * jj + 1) * 128 + c];
                    wpk[jj] = lo | (hi << 16);
                }
                uint4 o; o.x = wpk[0]; o.y = wpk[1]; o.z = wpk[2]; o.w = wpk[3];
                *(uint4*)(vtb + (size_t)c * 2048 + sg * 8) = o;
            }
        } else {
            // Q/K segments: coalesced 256B row stores
#pragma unroll
            for (int p = 0; p < 8; ++p) {
                int row = p * 16 + (tid >> 4);
                int c8 = (tid & 15) * 8;
                uint4 v = *(const uint4*)(EP + row * 128 + c8);
                *(uint4*)((uint16_t*)op + (size_t)(m0 + row) * 1024 + lc0 + c8) = v;
            }
        }
    }
}

// ---------------- causal flash attention: 256 thr, 4 waves x 32 q-rows ----------------
// r12-verified structure. BQ=128, BK=64, full K-range per block (2*qb+2 iters,
// max 32). Complementary qb pairing. K/V double-buffered in LDS (stride 72),
// reg-prefetched staging, one barrier per iter.
// SWAPPED QK^T: sc = mfma(K, Q) -> lane holds P^T fragment: q-row = l16,
// k-col = t*16 + quad*4 + r; 4 r-values LDS-contiguous -> one ds_write_b64
// per (mt,t) = 8 writes/iter; written layout IS the PV A-frag layout.
// CAUSAL EARLY-EXIT: in the final K-tile (k >= q0+64), waves 0,1 (q-rows
// < q0+64) are fully masked (P identically 0) -> they skip that iteration.
// Barrier-safe: the final iteration has no trailing barrier, and skipping
// waves still execute iteration niter-2 (incl. staging + its barrier).
__global__ __launch_bounds__(256) void attn_kernel(const uint16_t* __restrict__ Q,
                                                   const uint16_t* __restrict__ K,
                                                   const uint16_t* __restrict__ Vt,
                                                   uint16_t* __restrict__ att) {
    const int S = 2048, D = 1024;
    constexpr int LD = 72;                      // 144B rows = 9*16B aligned
    __shared__ __align__(16) uint16_t Klds[2][64 * LD];
    __shared__ __align__(16) uint16_t Vlds[2][64 * LD];
    __shared__ __align__(16) uint16_t Plds[4 * 32 * LD];

    const int bh = blockIdx.y;
    // complementary pairing across the two dispatch halves
    const int qb = (bh & 16) ? (int)blockIdx.x : 15 - (int)blockIdx.x;
    const int niter = 2 * qb + 2, kb_diag = 2 * qb;

    const int b = bh >> 4, h = bh & 15;
    const int tid = threadIdx.x, lane = tid & 63, w = tid >> 6;
    const int l16 = lane & 15, quad = lane >> 4;
    const int q0 = qb * 128;
    const size_t baseQK = (size_t)b * S * D + h * 64;
    uint16_t* Pw = Plds + w * (32 * LD);

    bf16x8 aq[2][2];
#pragma unroll
    for (int mt = 0; mt < 2; ++mt)
#pragma unroll
        for (int c = 0; c < 2; ++c)
            aq[mt][c] = *(const bf16x8*)(Q + baseQK +
                (size_t)(q0 + w * 32 + mt * 16 + l16) * D + c * 32 + quad * 8);

    bf16x8 ones;
#pragma unroll
    for (int j = 0; j < 8; ++j) ones[j] = (__bf16)1.0f;

    f32x4 accO[2][4] = {};
    f32x4 accL[2] = {};

    const int srow = tid >> 2, scq = tid & 3;   // staging: 64 rows x 4 col-groups of 16
    const uint16_t* Kg = K + baseQK + (size_t)srow * D + scq * 16;
    const uint16_t* Vg = Vt + ((size_t)bh * 64 + srow) * S + scq * 16;
    const int soff = srow * LD + scq * 16;

    // prologue: tile 0 regs -> LDS buf0; prefetch tile 1 into regs; one barrier
    uint4 kA, kB, vA, vB;
    kA = *(const uint4*)Kg; kB = *(const uint4*)(Kg + 8);
    vA = *(const uint4*)Vg; vB = *(const uint4*)(Vg + 8);
    *(uint4*)(Klds[0] + soff)     = kA;
    *(uint4*)(Klds[0] + soff + 8) = kB;
    *(uint4*)(Vlds[0] + soff)     = vA;
    *(uint4*)(Vlds[0] + soff + 8) = vB;
    {
        const uint16_t* kg = Kg + (size_t)64 * D;   // niter >= 2 always
        const uint16_t* vg = Vg + 64;
        kA = *(const uint4*)kg; kB = *(const uint4*)(kg + 8);
        vA = *(const uint4*)vg; vB = *(const uint4*)(vg + 8);
    }
    __syncthreads();

    // waves 0,1: final K-tile fully masked -> skip it (exact, barrier-safe)
    const int myniter = (w < 2) ? niter - 1 : niter;
    for (int kb = 0; kb < myniter; ++kb) {
        const uint16_t* Kb = Klds[kb & 1];
        const uint16_t* Vb = Vlds[kb & 1];

        // stage tile kb+1 into the other buffer (WAR safe across the barrier)
        if (kb + 1 < niter) {
            uint16_t* Kd = (uint16_t*)Klds[(kb + 1) & 1];
            uint16_t* Vd = (uint16_t*)Vlds[(kb + 1) & 1];
            *(uint4*)(Kd + soff)     = kA;
            *(uint4*)(Kd + soff + 8) = kB;
            *(uint4*)(Vd + soff)     = vA;
            *(uint4*)(Vd + soff + 8) = vB;
            if (kb + 2 < niter) {
                const uint16_t* kg = Kg + (size_t)((kb + 2) * 64) * D;
                const uint16_t* vg = Vg + (kb + 2) * 64;
                kA = *(const uint4*)kg; kB = *(const uint4*)(kg + 8);
                vA = *(const uint4*)vg; vB = *(const uint4*)(vg + 8);
            }
        }

        // ---- SWAPPED QK^T: sc[mt][t] = K_t * Q_mt -> D[kcol][qrow] ----
        f32x4 sc[2][4];
        __builtin_amdgcn_s_setprio(1);
#pragma unroll
        for (int t = 0; t < 4; ++t) {
            bf16x8 bk0 = *(const bf16x8*)(Kb + (t * 16 + l16) * LD + quad * 8);
            bf16x8 bk1 = *(const bf16x8*)(Kb + (t * 16 + l16) * LD + 32 + quad * 8);
            f32x4 z0 = {}; f32x4 z1 = {};
            sc[0][t] = mfma16(bk1, aq[0][1], mfma16(bk0, aq[0][0], z0));
            sc[1][t] = mfma16(bk1, aq[1][1], mfma16(bk0, aq[1][0], z1));
        }
        __builtin_amdgcn_s_setprio(0);

        // ---- V frags early ----
        bf16x8 bv0[4], bv1[4];
#pragma unroll
        for (int nt = 0; nt < 4; ++nt) {
            bv0[nt] = *(const bf16x8*)(Vb + (nt * 16 + l16) * LD + quad * 8);
            bv1[nt] = *(const bf16x8*)(Vb + (nt * 16 + l16) * LD + 32 + quad * 8);
        }

        // ---- p = 2^s (truncate to bf16), pack 4 r-values -> one b64 store ----
        // Pw[qrow][k] with qrow = mt*16+l16, k = t*16+quad*4+r  (A-frag layout)
        if (kb < kb_diag) {
#pragma unroll
            for (int mt = 0; mt < 2; ++mt) {
                uint16_t* prow = Pw + (mt * 16 + l16) * LD + quad * 4;
#pragma unroll
                for (int t = 0; t < 4; ++t) {
                    uint64_t pk = 0;
#pragma unroll
                    for (int r = 0; r < 4; ++r) {
                        float p = __builtin_amdgcn_exp2f(sc[mt][t][r]);
                        pk |= (uint64_t)(uint16_t)(__builtin_bit_cast(uint32_t, p) >> 16)
                              << (16 * r);
                    }
                    *(uint64_t*)(prow + t * 16) = pk;
                }
            }
        } else {
#pragma unroll
            for (int mt = 0; mt < 2; ++mt) {
                const int qrow = q0 + w * 32 + mt * 16 + l16;
                uint16_t* prow = Pw + (mt * 16 + l16) * LD + quad * 4;
#pragma unroll
                for (int t = 0; t < 4; ++t) {
                    const int kc0 = kb * 64 + t * 16 + quad * 4;
                    uint64_t pk = 0;
#pragma unroll
                    for (int r = 0; r < 4; ++r) {
                        float s = sc[mt][t][r];
                        if (kc0 + r > qrow) s = -1e30f;
                        float p = __builtin_amdgcn_exp2f(s);
                        pk |= (uint64_t)(uint16_t)(__builtin_bit_cast(uint32_t, p) >> 16)
                              << (16 * r);
                    }
                    *(uint64_t*)(prow + t * 16) = pk;
                }
            }
        }

        __asm__ volatile("s_waitcnt lgkmcnt(0)" ::: "memory");

        bf16x8 ap0[2], ap1[2];
#pragma unroll
        for (int mt = 0; mt < 2; ++mt) {
            ap0[mt] = *(const bf16x8*)(Pw + (mt * 16 + l16) * LD + quad * 8);
            ap1[mt] = *(const bf16x8*)(Pw + (mt * 16 + l16) * LD + 32 + quad * 8);
        }
        __builtin_amdgcn_s_setprio(1);
#pragma unroll
        for (int nt = 0; nt < 4; ++nt) {
            accO[0][nt] = mfma16(ap1[0], bv1[nt], mfma16(ap0[0], bv0[nt], accO[0][nt]));
            accO[1][nt] = mfma16(ap1[1], bv1[nt], mfma16(ap0[1], bv0[nt], accO[1][nt]));
        }
        // l row-sums of the exact stored bf16 P (all 16 output cols equal)
        accL[0] = mfma16(ap1[0], ones, mfma16(ap0[0], ones, accL[0]));
        accL[1] = mfma16(ap1[1], ones, mfma16(ap0[1], ones, accL[1]));
        __builtin_amdgcn_s_setprio(0);

        if (kb + 1 < niter) __syncthreads();   // publishes buf (kb+1)&1
    }

    // ---- normalize into per-wave Pw (32x64 bf16), coalesced stores ----
    __asm__ volatile("s_waitcnt lgkmcnt(0)" ::: "memory");  // ap frag reads done
#pragma unroll
    for (int mt = 0; mt < 2; ++mt)
#pragma unroll
        for (int r = 0; r < 4; ++r) {
            float inv = __builtin_amdgcn_rcpf(accL[mt][r]);
            const int rl = mt * 16 + quad * 4 + r;
#pragma unroll
            for (int nt = 0; nt < 4; ++nt)
                Pw[rl * LD + nt * 16 + l16] = f2bf(accO[mt][nt][r] * inv);
        }
    __asm__ volatile("s_waitcnt lgkmcnt(0)" ::: "memory");
#pragma unroll
    for (int p = 0; p < 4; ++p) {
        int row = p * 8 + (lane >> 3);          // 0..31 within wave's q-rows
        int c8 = (lane & 7) * 8;                // 0..56 within head dims (16B steps)
        uint4 v = *(const uint4*)(Pw + row * LD + c8);
        *(uint4*)(att + (size_t)(b * S + q0 + w * 32 + row) * 1024 + h * 64 + c8) = v;
    }
}

extern "C" void kernel_launch(void* const* d_in, const int* in_sizes, int n_in,
                              void* d_out, int out_size, void* d_ws, size_t ws_size,
                              hipStream_t stream) {
    const float* x  = (const float*)d_in[0];
    // d_in[1] = mask: known causal, unused
    const float* Wq = (const float*)d_in[2];
    const float* bq = (const float*)d_in[3];
    const float* Wk = (const float*)d_in[4];
    const float* bk = (const float*)d_in[5];
    const float* Wv = (const float*)d_in[6];
    const float* bv = (const float*)d_in[7];
    const float* Wo = (const float*)d_in[8];
    const float* bo = (const float*)d_in[9];
    float* out = (float*)d_out;

    const int B = 2, S = 2048, D = 1024, H = 16;
    const int M = B * S;  // 4096

    uint8_t* w = (uint8_t*)d_ws;
    uint16_t* xbf  = (uint16_t*)(w);                       // 8 MB (aliased by att)
    uint16_t* wqbf = (uint16_t*)(w + (size_t)( 8 << 20));  // wq/wk/wv/wo contiguous
    uint16_t* qbf  = (uint16_t*)(w + (size_t)(16 << 20));
    uint16_t* kbf  = (uint16_t*)(w + (size_t)(24 << 20));
    uint16_t* vtbf = (uint16_t*)(w + (size_t)(40 << 20));  // V written transposed by QKV GEMM
    uint16_t* wobf = wqbf + (size_t)3 * D * D;
    uint16_t* attbf = xbf;                                 // x dead after QKV GEMM

    // fused cast: x (1<<20 float4) + 4 weights (4 * 1<<18 float4) = 1<<21 quads
    cast_all<<<dim3((1 << 21) / 256), dim3(256), 0, stream>>>(
        x, Wq, Wk, Wv, Wo, xbf, wqbf);

    // fused QKV: A[4096,1024] x W[3072,1024]^T ; Q scaled by 0.125*log2(e);
    // V segment written transposed into vtbf (o2)
    gemm128<0, 128><<<dim3(M / 128, 3072 / 128), dim3(256), 0, stream>>>(
        xbf, wqbf, bq, bk, bv, qbf, kbf, vtbf, D, 0.125f * 1.44269504f, 1.0f, 1.0f);

    // causal attention: 16 q-blocks x 32 (b,h), 256 threads, complementary pairing
    attn_kernel<<<dim3(16, B * H), dim3(256), 0, stream>>>(qbf, kbf, vtbf, attbf);

    // O-proj: 128x64 tiles -> 512 blocks = 2 blocks/CU
    gemm128<1, 64><<<dim3(M / 128, 1024 / 64), dim3(256), 0, stream>>>(
        attbf, wobf, bo, bo, bo, out, out, out, D, 1.0f, 1.0f, 1.0f);
}